// Round 3
// baseline (1272.392 us; speedup 1.0000x reference)
//
#include <hip/hip_runtime.h>
#include <hip/hip_bf16.h>

// Decomposable attention, bf16-MFMA pipeline, chunked (Bh per side per chunk).
// R11: gemm256 (256^2, 8-phase) checkpoint spacing fixed: FOUR counted-vmcnt
// checkpoints per iteration (vmcnt(8) at P2/P4/P6/P8), each draining exactly
// one A+B stage-unit issued >=4 phases earlier (R9 had 2 checkpoints with
// 2-phase-old drains -> load-latency stall at every checkpoint, 97us vs 74us
// baseline). Stages issue before ds_reads in each phase. Swizzle, LDS layout,
// epilogues, and all non-big-GEMM kernels unchanged.

using f32x4 = __attribute__((ext_vector_type(4))) float;
using s16x8 = __attribute__((ext_vector_type(8))) short;

__device__ __forceinline__ void gload_lds16(const short* g, short* l) {
  __builtin_amdgcn_global_load_lds(
      (const __attribute__((address_space(1))) unsigned int*)g,
      (__attribute__((address_space(3))) unsigned int*)l, 16, 0, 0);
}

// ---------------- 256^2 8-phase GEMM: C[M,N] = A[M,K] * B[N,K]^T ------------
// grid = (N/256, M/256), block = 512 (8 waves, 2M x 4N). K % 128 == 0.
// LDS per operand: [buf][kk][256 rows][32 k] bf16; row = 64 B = 4 chunks of
// 16 B, slot = chunk ^ ((row>>1)&3). Staged via global_load_lds with
// pre-swizzled global source (linear LDS dest). Always bias+relu.
// Stage units: X(T).kk = 256 rows x 32 k of one operand = 2 vmem instr/wave.
// Issue->drain ages all >=4 phases under the P2/P4/P6/P8 vmcnt(8) checkpoints.
template <bool SUML>
__global__ __launch_bounds__(512, 2) void gemm256(
    const short* __restrict__ A, const short* __restrict__ B,
    const float* __restrict__ bias, void* __restrict__ Cv, int K, int lda,
    int ldb, int ldc, int split) {
  __shared__ __align__(16) short As[2 * 2 * 8192];
  __shared__ __align__(16) short Bs[2 * 2 * 8192];

  const int t = threadIdx.x;
  const int lane = t & 63;
  const int w = t >> 6;
  const int wm = w >> 2;  // 0..1
  const int wn = w & 3;   // 0..3

  // XCD-aware swizzle: contiguous tile range per XCD.
  unsigned bx = blockIdx.x, by = blockIdx.y;
  {
    unsigned flat = by * gridDim.x + bx;
    unsigned total = gridDim.x * gridDim.y;
    if ((total & 7u) == 0) {
      unsigned nf = (flat & 7u) * (total >> 3) + (flat >> 3);
      bx = nf % gridDim.x;
      by = nf / gridDim.x;
    }
  }
  const int m0 = by * 256;
  const int n0 = bx * 256;

  // ---- staging geometry: issue q covers rows (w*2+q)*16..+16, lane covers
  // row +(lane>>2), LDS slot lane&3, global chunk (lane&3)^((row>>1)&3). ----
  const short* gA[2];
  const short* gB[2];
  short* lA[2];
  short* lB[2];
#pragma unroll
  for (int q = 0; q < 2; ++q) {
    const int r = (w * 2 + q) * 16 + (lane >> 2);
    const int cg = (lane & 3) ^ ((r >> 1) & 3);
    gA[q] = A + (long)(m0 + r) * lda + cg * 8;
    gB[q] = B + (long)(n0 + r) * ldb + cg * 8;
    lA[q] = As + (w * 2 + q) * 512;
    lB[q] = Bs + (w * 2 + q) * 512;
  }

  // ---- fragment read offsets (shorts). Row stride 32 shorts; swizzle
  // invariant across mf/nf (16-row steps keep (r>>1)&3). ----
  const int c4 = lane >> 4;
  const int rA0 = wm * 128 + (lane & 15);
  const int rB0 = wn * 64 + (lane & 15);
  const int aoff0 = rA0 * 32 + ((c4 ^ ((rA0 >> 1) & 3)) * 8);
  const int boff0 = rB0 * 32 + ((c4 ^ ((rB0 >> 1) & 3)) * 8);

  f32x4 acc[8][4] = {};
  s16x8 af[8], bf[2];

  const int nIter = K >> 7;  // two 64-wide K-tiles per iteration

  auto stgA = [&](int koff, int roff) {
#pragma unroll
    for (int q = 0; q < 2; ++q) gload_lds16(gA[q] + koff, lA[q] + roff);
  };
  auto stgB = [&](int koff, int roff) {
#pragma unroll
    for (int q = 0; q < 2; ++q) gload_lds16(gB[q] + koff, lB[q] + roff);
  };
  auto rdA = [&](int reg) {
#pragma unroll
    for (int m = 0; m < 8; ++m)
      af[m] = *(const s16x8*)(As + reg + aoff0 + m * 512);
  };
  auto rdB = [&](int reg, int np) {
#pragma unroll
    for (int n = 0; n < 2; ++n)
      bf[n] = *(const s16x8*)(Bs + reg + boff0 + (np * 2 + n) * 512);
  };
  auto mf16 = [&](int np) {
    __builtin_amdgcn_s_setprio(1);
#pragma unroll
    for (int m = 0; m < 8; ++m)
#pragma unroll
      for (int n = 0; n < 2; ++n)
        acc[m][np * 2 + n] = __builtin_amdgcn_mfma_f32_16x16x32_bf16(
            af[m], bf[n], acc[m][np * 2 + n], 0, 0, 0);
    __builtin_amdgcn_s_setprio(0);
  };

  // ---- prologue: stage (0).k0, (0).k1, (1).k0; drain only (0).k0 ----
  stgA(0, 0);
  stgB(0, 0);
  stgA(32, 8192);
  stgB(32, 8192);
  stgA(64, 16384);
  stgB(64, 16384);
  asm volatile("s_waitcnt vmcnt(8)" ::: "memory");
  __builtin_amdgcn_sched_barrier(0);
  __builtin_amdgcn_s_barrier();

  for (int i = 0; i < nIter; ++i) {
    const int kb = i * 128;  // shorts; iter handles tiles 2i (buf0), 2i+1 (buf1)
    const bool more = (i + 1 < nIter);

    // P1: stage A(2i+1).k1 -> buf1.kk1; compute (buf0,kk0,nf01)
    stgA(kb + 96, 24576);
    rdA(0);
    rdB(0, 0);
    __builtin_amdgcn_s_barrier();
    asm volatile("s_waitcnt lgkmcnt(0)" ::: "memory");
    __builtin_amdgcn_sched_barrier(0);
    mf16(0);
    __builtin_amdgcn_s_barrier();

    // P2: stage B(2i+1).k1; compute (buf0,kk0,nf23); ckpt drains (2i).k1
    stgB(kb + 96, 24576);
    rdB(0, 1);
    __builtin_amdgcn_s_barrier();
    asm volatile("s_waitcnt lgkmcnt(0)" ::: "memory");
    __builtin_amdgcn_sched_barrier(0);
    mf16(1);
    asm volatile("s_waitcnt vmcnt(8)" ::: "memory");
    __builtin_amdgcn_sched_barrier(0);
    __builtin_amdgcn_s_barrier();

    // P3: stage A(2i+2).k0 -> buf0.kk0 (readers done at P2); compute (buf0,kk1,nf01)
    if (more) stgA(kb + 128, 0);
    rdA(8192);
    rdB(8192, 0);
    __builtin_amdgcn_s_barrier();
    asm volatile("s_waitcnt lgkmcnt(0)" ::: "memory");
    __builtin_amdgcn_sched_barrier(0);
    mf16(0);
    __builtin_amdgcn_s_barrier();

    // P4: stage B(2i+2).k0; compute (buf0,kk1,nf23); ckpt drains (2i+1).k0
    if (more) stgB(kb + 128, 0);
    rdB(8192, 1);
    __builtin_amdgcn_s_barrier();
    asm volatile("s_waitcnt lgkmcnt(0)" ::: "memory");
    __builtin_amdgcn_sched_barrier(0);
    mf16(1);
    if (more) {
      asm volatile("s_waitcnt vmcnt(8)" ::: "memory");
    } else {
      asm volatile("s_waitcnt vmcnt(4)" ::: "memory");
    }
    __builtin_amdgcn_sched_barrier(0);
    __builtin_amdgcn_s_barrier();

    // P5: stage A(2i+2).k1 -> buf0.kk1; compute (buf1,kk0,nf01)
    if (more) stgA(kb + 160, 8192);
    rdA(16384);
    rdB(16384, 0);
    __builtin_amdgcn_s_barrier();
    asm volatile("s_waitcnt lgkmcnt(0)" ::: "memory");
    __builtin_amdgcn_sched_barrier(0);
    mf16(0);
    __builtin_amdgcn_s_barrier();

    // P6: stage B(2i+2).k1; compute (buf1,kk0,nf23); ckpt drains (2i+1).k1
    if (more) stgB(kb + 160, 8192);
    rdB(16384, 1);
    __builtin_amdgcn_s_barrier();
    asm volatile("s_waitcnt lgkmcnt(0)" ::: "memory");
    __builtin_amdgcn_sched_barrier(0);
    mf16(1);
    if (more) {
      asm volatile("s_waitcnt vmcnt(8)" ::: "memory");
    } else {
      asm volatile("s_waitcnt vmcnt(0)" ::: "memory");
    }
    __builtin_amdgcn_sched_barrier(0);
    __builtin_amdgcn_s_barrier();

    // P7: stage A(2i+3).k0 -> buf1.kk0; compute (buf1,kk1,nf01)
    if (more) stgA(kb + 192, 16384);
    rdA(24576);
    rdB(24576, 0);
    __builtin_amdgcn_s_barrier();
    asm volatile("s_waitcnt lgkmcnt(0)" ::: "memory");
    __builtin_amdgcn_sched_barrier(0);
    mf16(0);
    __builtin_amdgcn_s_barrier();

    // P8: stage B(2i+3).k0; compute (buf1,kk1,nf23); ckpt drains (2i+2).k0
    if (more) stgB(kb + 192, 16384);
    rdB(24576, 1);
    __builtin_amdgcn_s_barrier();
    asm volatile("s_waitcnt lgkmcnt(0)" ::: "memory");
    __builtin_amdgcn_sched_barrier(0);
    mf16(1);
    if (more) {
      asm volatile("s_waitcnt vmcnt(8)" ::: "memory");
    } else {
      asm volatile("s_waitcnt vmcnt(0)" ::: "memory");
    }
    __builtin_amdgcn_sched_barrier(0);
    __builtin_amdgcn_s_barrier();
  }

  // ---- epilogue: C/D layout col=lane&15, row=(lane>>4)*4+reg ----
  const int ccol = lane & 15;
  const int crow = (lane >> 4) * 4;
  if constexpr (!SUML) {
#pragma unroll
    for (int j = 0; j < 4; ++j) {
      const int col = n0 + wn * 64 + j * 16 + ccol;
      const float bj = bias[col];
#pragma unroll
      for (int m = 0; m < 8; ++m) {
        const int row0 = m0 + wm * 128 + m * 16 + crow;
#pragma unroll
        for (int r = 0; r < 4; ++r) {
          float x = fmaxf(acc[m][j][r] + bj, 0.f);
          ((__hip_bfloat16*)Cv)[(long)(row0 + r) * ldc + col] =
              __float2bfloat16(x);
        }
      }
    }
  } else {
    __shared__ float ssum[256];
    __syncthreads();
    if (t < 256) ssum[t] = 0.f;
    __syncthreads();
#pragma unroll
    for (int j = 0; j < 4; ++j) {
      const int lcol = wn * 64 + j * 16 + ccol;
      const float bj = bias[n0 + lcol];
      float part = 0.f;
#pragma unroll
      for (int m = 0; m < 8; ++m)
#pragma unroll
        for (int r = 0; r < 4; ++r) part += fmaxf(acc[m][j][r] + bj, 0.f);
      atomicAdd(&ssum[lcol], part);
    }
    __syncthreads();
    if (t < 256) {
      int rb2 = m0 >> 8;
      const int side = rb2 >= split;
      rb2 -= side * split;
      atomicAdd((float*)Cv + (long)rb2 * ldc + side * (ldc >> 1) + n0 + t,
                ssum[t]);
    }
  }
}

// ---------------- GEMM: C[M,N] = A[M,K] * B[N,K]^T (+bias, relu) ----------------
// grid = (N/128, M/128, batch), block = 256. K % 64 == 0. (128^2 kernel kept
// for e1 / att+concat / aggregate GEMMs.)
template <bool RELU, bool OUT_BF16, bool HAS_BIAS, bool SUML, bool CONCAT>
__global__ __launch_bounds__(256, 4) void gemm_nt(
    const short* __restrict__ A, const short* __restrict__ B,
    const float* __restrict__ bias, void* __restrict__ Cv, int K, int lda,
    int ldb, int ldc, long sA, long sB, long sC, const float* __restrict__ cs1,
    const float* __restrict__ cs2, int cBh) {
  __shared__ __align__(16) short As[128 * 64];
  __shared__ __align__(16) short Bs[128 * 64];
  const int t = threadIdx.x;
  const int lane = t & 63;
  const int wave = t >> 6;

  unsigned flat = (blockIdx.z * gridDim.y + blockIdx.y) * gridDim.x + blockIdx.x;
  const unsigned total = gridDim.x * gridDim.y * gridDim.z;
  unsigned bx = blockIdx.x, by = blockIdx.y, bz = blockIdx.z;
  if ((total & 7u) == 0) {
    unsigned nf = (flat & 7u) * (total >> 3) + (flat >> 3);
    bx = nf % gridDim.x;
    unsigned rest = nf / gridDim.x;
    by = rest % gridDim.y;
    bz = rest / gridDim.y;
  }
  const int m0 = by * 128;
  const int n0 = bx * 128;
  const long zb = bz;

  const int srow = t >> 3;
  const int schunk = ((t & 7) ^ (srow & 7)) * 8;
  const short* ag = A + zb * sA + (long)(m0 + srow) * lda + schunk;
  const short* bg = B + zb * sB + (long)(n0 + srow) * ldb + schunk;
  const long a32 = (long)32 * lda, b32 = (long)32 * ldb;
  short* AsW = As + wave * 512;
  short* BsW = Bs + wave * 512;

  const int fr = lane & 15;
  const int kq = lane >> 4;
  int aoff[4], boff[4];
#pragma unroll
  for (int i = 0; i < 4; ++i) {
    const int ra = (wave >> 1) * 64 + i * 16 + fr;
    const int rb = (wave & 1) * 64 + i * 16 + fr;
    aoff[i] = ra * 64 + ((kq ^ (ra & 7)) * 8);
    boff[i] = rb * 64 + ((kq ^ (rb & 7)) * 8);
  }

  f32x4 acc[4][4] = {};

  for (int it = K >> 6; it > 0; --it) {
    gload_lds16(ag, AsW);
    gload_lds16(ag + a32, AsW + 2048);
    gload_lds16(ag + 2 * a32, AsW + 4096);
    gload_lds16(ag + 3 * a32, AsW + 6144);
    gload_lds16(bg, BsW);
    gload_lds16(bg + b32, BsW + 2048);
    gload_lds16(bg + 2 * b32, BsW + 4096);
    gload_lds16(bg + 3 * b32, BsW + 6144);
    ag += 64;
    bg += 64;
    __syncthreads();
#pragma unroll
    for (int kk = 0; kk < 2; ++kk) {
      const int x = kk * 32;
      s16x8 af[4], bfv[4];
#pragma unroll
      for (int i = 0; i < 4; ++i) af[i] = *(const s16x8*)(As + (aoff[i] ^ x));
#pragma unroll
      for (int j = 0; j < 4; ++j) bfv[j] = *(const s16x8*)(Bs + (boff[j] ^ x));
#pragma unroll
      for (int i = 0; i < 4; ++i)
#pragma unroll
        for (int j = 0; j < 4; ++j)
          acc[i][j] = __builtin_amdgcn_mfma_f32_16x16x32_bf16(
              af[i], bfv[j], acc[i][j], 0, 0, 0);
    }
    __syncthreads();
  }

  const int ccol = lane & 15;
  const int crow = (lane >> 4) * 4;

  if constexpr (SUML) {
    __shared__ float ssum[128];
    if (t < 128) ssum[t] = 0.f;
    __syncthreads();
#pragma unroll
    for (int j = 0; j < 4; ++j) {
      const int lcol = (wave & 1) * 64 + j * 16 + ccol;
      float bj = HAS_BIAS ? bias[n0 + lcol] : 0.f;
      float part = 0.f;
#pragma unroll
      for (int i = 0; i < 4; ++i)
#pragma unroll
        for (int r = 0; r < 4; ++r) {
          float x = acc[i][j][r] + bj;
          if (RELU) x = fmaxf(x, 0.f);
          part += x;
        }
      atomicAdd(&ssum[lcol], part);
    }
    __syncthreads();
    if (t < 128) {
      const int split = (int)sC;
      int rb2 = m0 >> 8;
      const int side = rb2 >= split;
      rb2 -= side * split;
      atomicAdd((float*)Cv + (long)rb2 * ldc + side * (ldc >> 1) + n0 + t,
                ssum[t]);
    }
  } else {
#pragma unroll
    for (int j = 0; j < 4; ++j) {
      const int col = n0 + (wave & 1) * 64 + j * 16 + ccol;
      float bj = 0.f;
      if (HAS_BIAS) bj = bias[col];
#pragma unroll
      for (int i = 0; i < 4; ++i) {
        const int row0 = m0 + (wave >> 1) * 64 + i * 16 + crow;
#pragma unroll
        for (int r = 0; r < 4; ++r) {
          float x = acc[i][j][r] + bj;
          if (RELU) x = fmaxf(x, 0.f);
          const long idx = (long)(row0 + r) * ldc + col + zb * sC;
          if (OUT_BF16)
            ((__hip_bfloat16*)Cv)[idx] = __float2bfloat16(x);
          else
            ((float*)Cv)[idx] = x;
        }
      }
    }
    if constexpr (CONCAT) {
      const int side = (int)(zb >= (long)cBh);
      const int bb = (int)zb - side * cBh;
      const float* csrc = side ? cs2 : cs1;
      const long crowbase = (long)bb * 256;
      __hip_bfloat16* Cb = (__hip_bfloat16*)Cv + zb * sC + 512 + n0;
#pragma unroll
      for (int k = 0; k < 16; ++k) {
        const int idx = k * 256 + t;
        const int r = idx >> 5;
        const int q = idx & 31;
        const float4 v =
            *(const float4*)(csrc + (crowbase + m0 + r) * 512 + n0 + q * 4);
        union {
          ushort4 u;
          __hip_bfloat16 h[4];
        } pk;
        pk.h[0] = __float2bfloat16(v.x);
        pk.h[1] = __float2bfloat16(v.y);
        pk.h[2] = __float2bfloat16(v.z);
        pk.h[3] = __float2bfloat16(v.w);
        *(ushort4*)(Cb + (long)(m0 + r) * ldc + q * 4) = pk.u;
      }
    }
  }
}

// ---------------- helpers ----------------
struct CastArgs {
  const float* src[6];
  __hip_bfloat16* dst[6];
  long n[6];
};
__global__ void cast_many(CastArgs a) {
  const int w = blockIdx.y;
  long i = ((long)blockIdx.x * blockDim.x + threadIdx.x) * 4;
  if (i >= a.n[w]) return;
  float4 v = *(const float4*)(a.src[w] + i);
  __hip_bfloat16* o = a.dst[w] + i;
  o[0] = __float2bfloat16(v.x);
  o[1] = __float2bfloat16(v.y);
  o[2] = __float2bfloat16(v.z);
  o[3] = __float2bfloat16(v.w);
}

__global__ void cast_bf16(const float* __restrict__ in,
                          __hip_bfloat16* __restrict__ out, long n) {
  long i = ((long)blockIdx.x * blockDim.x + threadIdx.x) * 4;
  if (i >= n) return;
  float4 v = *(const float4*)(in + i);
  out[i + 0] = __float2bfloat16(v.x);
  out[i + 1] = __float2bfloat16(v.y);
  out[i + 2] = __float2bfloat16(v.z);
  out[i + 3] = __float2bfloat16(v.w);
}

__global__ void prep_sent(const float* __restrict__ s1,
                          const float* __restrict__ s2,
                          __hip_bfloat16* __restrict__ S12b,
                          __hip_bfloat16* __restrict__ STbase, int Bh) {
  __shared__ float tile[32][33];
  const int z = blockIdx.z;
  const int e0 = blockIdx.x * 32;
  const int l0 = blockIdx.y * 32;
  const int side = z >= Bh;
  const int b = z - side * Bh;
  const float* ib = (side ? s2 : s1) + (long)b * 131072;
  __hip_bfloat16* on = S12b + (long)z * 131072;
  __hip_bfloat16* ot = STbase + (long)(side ? b : (Bh + b)) * 131072;
  const int tx = threadIdx.x, ty = threadIdx.y;
#pragma unroll
  for (int k = 0; k < 4; ++k) {
    const int l = l0 + ty + 8 * k;
    const float v = ib[(long)l * 512 + e0 + tx];
    on[(long)l * 512 + e0 + tx] = __float2bfloat16(v);
    tile[ty + 8 * k][tx] = v;
  }
  __syncthreads();
#pragma unroll
  for (int k = 0; k < 4; ++k)
    ot[(long)(e0 + ty + 8 * k) * 256 + l0 + tx] =
        __float2bfloat16(tile[tx][ty + 8 * k]);
}

__global__ void softmax_rows(const float* __restrict__ E,
                             __hip_bfloat16* __restrict__ W) {
  const long row = blockIdx.x;
  const int t = threadIdx.x;
  const float x = E[row * 256 + t];
  float m = x;
  for (int o = 32; o > 0; o >>= 1) m = fmaxf(m, __shfl_xor(m, o));
  __shared__ float red[4];
  if ((t & 63) == 0) red[t >> 6] = m;
  __syncthreads();
  m = fmaxf(fmaxf(red[0], red[1]), fmaxf(red[2], red[3]));
  const float pr = __expf(x - m);
  float s = pr;
  for (int o = 32; o > 0; o >>= 1) s += __shfl_xor(s, o);
  __shared__ float red2[4];
  if ((t & 63) == 0) red2[t >> 6] = s;
  __syncthreads();
  s = red2[0] + red2[1] + red2[2] + red2[3];
  W[row * 256 + t] = __float2bfloat16(pr / s);
}

__global__ __launch_bounds__(256) void softmax_cols_f(
    const float* __restrict__ E, __hip_bfloat16* __restrict__ W) {
  __shared__ float tile[256][65];
  __shared__ float mred[4][64], sred[4][64];
  const int b = blockIdx.y;
  const int j0 = blockIdx.x * 64;
  const int t = threadIdx.x;
  const int jl = t & 63, s = t >> 6;
  const float* Eb = E + (long)b * 65536 + j0;
#pragma unroll
  for (int k = 0; k < 64; ++k) {
    const int i = k * 4 + s;
    tile[i][jl] = Eb[(long)i * 256 + jl];
  }
  __syncthreads();
  float m = -3.4e38f;
#pragma unroll 8
  for (int r = 0; r < 64; ++r) m = fmaxf(m, tile[s * 64 + r][jl]);
  mred[s][jl] = m;
  __syncthreads();
  m = fmaxf(fmaxf(mred[0][jl], mred[1][jl]), fmaxf(mred[2][jl], mred[3][jl]));
  float sum = 0.f;
#pragma unroll 8
  for (int r = 0; r < 64; ++r) sum += __expf(tile[s * 64 + r][jl] - m);
  sred[s][jl] = sum;
  __syncthreads();
  const int jw = t >> 2;
  const int ib = t & 3;
  const float mj = fmaxf(fmaxf(mred[0][jw], mred[1][jw]),
                         fmaxf(mred[2][jw], mred[3][jw]));
  const float isj =
      1.0f / (sred[0][jw] + sred[1][jw] + sred[2][jw] + sred[3][jw]);
  __hip_bfloat16* Wb = W + (long)b * 65536 + (long)(j0 + jw) * 256 + ib * 64;
#pragma unroll 8
  for (int r = 0; r < 64; ++r)
    Wb[r] = __float2bfloat16(__expf(tile[ib * 64 + r][jw] - mj) * isj);
}

__global__ void final_lin(const __hip_bfloat16* __restrict__ h2,
                          const float* __restrict__ w,
                          const float* __restrict__ bs,
                          float* __restrict__ out) {
  const int b = blockIdx.x;
  const int t = threadIdx.x;
  float p0 = 0.f, p1 = 0.f, p2 = 0.f;
  for (int k = t; k < 1024; k += 256) {
    const float x = __bfloat162float(h2[(long)b * 1024 + k]);
    p0 += x * w[k];
    p1 += x * w[1024 + k];
    p2 += x * w[2048 + k];
  }
  for (int o = 32; o > 0; o >>= 1) {
    p0 += __shfl_xor(p0, o);
    p1 += __shfl_xor(p1, o);
    p2 += __shfl_xor(p2, o);
  }
  __shared__ float r[4][3];
  if ((t & 63) == 0) {
    r[t >> 6][0] = p0;
    r[t >> 6][1] = p1;
    r[t >> 6][2] = p2;
  }
  __syncthreads();
  if (t < 3)
    out[b * 3 + t] = r[0][t] + r[1][t] + r[2][t] + r[3][t] + bs[t];
}

extern "C" void kernel_launch(void* const* d_in, const int* in_sizes, int n_in,
                              void* d_out, int out_size, void* d_ws,
                              size_t ws_size, hipStream_t stream) {
  const float* sent1 = (const float*)d_in[0];
  const float* sent2 = (const float*)d_in[1];
  const float* f_w1 = (const float*)d_in[2];
  const float* f_b1 = (const float*)d_in[3];
  const float* f_w2 = (const float*)d_in[4];
  const float* f_b2 = (const float*)d_in[5];
  const float* g_w1 = (const float*)d_in[6];
  const float* g_b1 = (const float*)d_in[7];
  const float* g_w2 = (const float*)d_in[8];
  const float* g_b2 = (const float*)d_in[9];
  const float* h_w1 = (const float*)d_in[10];
  const float* h_b1 = (const float*)d_in[11];
  const float* h_w2 = (const float*)d_in[12];
  const float* h_b2 = (const float*)d_in[13];
  const float* fin_w = (const float*)d_in[14];
  const float* fin_b = (const float*)d_in[15];

  char* p = (char*)d_ws;
  auto take = [&](size_t n) {
    char* r = p;
    p += (n + 255) & ~(size_t)255;
    return r;
  };
  const int Bh = (ws_size >= (size_t)220 * 1024 * 1024) ? 64 : 32;
  const int chunks = 128 / Bh;
  const long R = (long)Bh * 256;

  short* Wf1 = (short*)take(1024L * 512 * 2);
  short* Wf2 = (short*)take(1024L * 1024 * 2);
  short* Wg1 = (short*)take(1024L * 1024 * 2);
  short* Wg2 = (short*)take(1024L * 1024 * 2);
  short* Wh1 = (short*)take(1024L * 2048 * 2);
  short* Wh2 = (short*)take(1024L * 1024 * 2);
  float* SUMF = (float*)take(128L * 2048 * 4);
  short* scat = (short*)take(128L * 2048 * 2);
  short* hh = (short*)take(128L * 1024 * 2);
  short* hf = (short*)take(128L * 1024 * 2);
  char* Areg = take(2 * R * 1024 * 2);  // FHID -> GHID
  char* Breg = take(2 * R * 1024 * 2);  // F12 -> CC12
  char* Creg = take(2 * R * 512 * 2);   // S12b -> E1|W1A|W2A
  char* Dreg = take(2 * R * 512 * 2);   // [S2T | S1T]
  (void)in_sizes; (void)n_in; (void)out_size;

  short* FHID = (short*)Areg;
  short* GHID = (short*)Areg;
  short* F12 = (short*)Breg;
  short* CC12 = (short*)Breg;
  short* S12b = (short*)Creg;
  float* E1 = (float*)Creg;
  short* W1A = (short*)(Creg + (long)Bh * 262144);
  short* W2A = W1A + (long)Bh * 65536;
  short* ST = (short*)Dreg;

  hipMemsetAsync(SUMF, 0, 128L * 2048 * 4, stream);

  CastArgs ca;
  ca.src[0] = f_w1; ca.dst[0] = (__hip_bfloat16*)Wf1; ca.n[0] = 524288;
  ca.src[1] = f_w2; ca.dst[1] = (__hip_bfloat16*)Wf2; ca.n[1] = 1048576;
  ca.src[2] = g_w1; ca.dst[2] = (__hip_bfloat16*)Wg1; ca.n[2] = 1048576;
  ca.src[3] = g_w2; ca.dst[3] = (__hip_bfloat16*)Wg2; ca.n[3] = 1048576;
  ca.src[4] = h_w1; ca.dst[4] = (__hip_bfloat16*)Wh1; ca.n[4] = 2097152;
  ca.src[5] = h_w2; ca.dst[5] = (__hip_bfloat16*)Wh2; ca.n[5] = 1048576;
  cast_many<<<dim3(2048, 6), 256, 0, stream>>>(ca);

  for (int c = 0; c < chunks; ++c) {
    const float* s1 = sent1 + (long)c * R * 512;
    const float* s2 = sent2 + (long)c * R * 512;
    float* SUMF_c = SUMF + (long)c * Bh * 2048;
    const int MT2 = (int)(2 * R / 256);

    prep_sent<<<dim3(16, 8, 2 * Bh), dim3(32, 8), 0, stream>>>(
        s1, s2, (__hip_bfloat16*)S12b, (__hip_bfloat16*)ST, Bh);

    // ---- attend MLP f (merged sides, M = 2R), 256^2 8-phase kernel ----
    gemm256<false><<<dim3(4, MT2), 512, 0, stream>>>(
        S12b, Wf1, f_b1, FHID, 512, 512, 512, 1024, 0);
    gemm256<false><<<dim3(4, MT2), 512, 0, stream>>>(
        FHID, Wf2, f_b2, F12, 1024, 1024, 1024, 1024, 0);

    // ---- e1 = F1 F2^T (batched fp32; overwrites S12b region) ----
    gemm_nt<false, false, false, false, false><<<dim3(2, 2, Bh), 256, 0, stream>>>(
        F12, F12 + R * 1024, nullptr, E1, 1024, 1024, 1024, 256, 256L * 1024,
        256L * 1024, 65536, nullptr, nullptr, 0);

    // ---- softmaxes ----
    softmax_rows<<<Bh * 256, 256, 0, stream>>>(E1, (__hip_bfloat16*)W1A);
    softmax_cols_f<<<dim3(4, Bh), 256, 0, stream>>>(E1, (__hip_bfloat16*)W2A);

    // ---- att (merged) + fused coalesced concat right-half fill ----
    gemm_nt<false, true, false, false, true><<<dim3(4, 2, 2 * Bh), 256, 0, stream>>>(
        W1A, ST, nullptr, CC12, 256, 256, 256, 1024, 65536, 131072, 262144,
        s1, s2, Bh);

    // ---- compare MLP g (merged); layer2 accumulates sum-over-L ----
    gemm256<false><<<dim3(4, MT2), 512, 0, stream>>>(
        CC12, Wg1, g_b1, GHID, 1024, 1024, 1024, 1024, 0);
    gemm256<true><<<dim3(4, MT2), 512, 0, stream>>>(
        GHID, Wg2, g_b2, SUMF_c, 1024, 1024, 1024, 2048, Bh);
  }

  // ---- aggregate MLP h + final linear ----
  cast_bf16<<<256, 256, 0, stream>>>(SUMF, (__hip_bfloat16*)scat, 262144);
  gemm_nt<true, true, true, false, false><<<dim3(8, 1, 1), 256, 0, stream>>>(
      scat, Wh1, h_b1, hh, 2048, 2048, 2048, 1024, 0, 0, 0, nullptr, nullptr, 0);
  gemm_nt<true, true, true, false, false><<<dim3(8, 1, 1), 256, 0, stream>>>(
      hh, Wh2, h_b2, hf, 1024, 1024, 1024, 1024, 0, 0, 0, nullptr, nullptr, 0);
  final_lin<<<128, 256, 0, stream>>>((__hip_bfloat16*)hf, fin_w, fin_b,
                                     (float*)d_out);
}

// Round 5
// 1019.667 us; speedup vs baseline: 1.2479x; 1.2479x over previous
//
#include <hip/hip_runtime.h>
#include <hip/hip_bf16.h>

// Decomposable attention, bf16-MFMA pipeline, chunked (Bh per side per chunk).
// R12: revert f1/f2/g2 to the proven 128^2 gemm_nt (932 TF, R8 config).
// Probe: g1 only runs gemm256L - a LIGHT-TOUCH 8-phase 256^2 kernel with
// R11's verified publish/lifetime schedule (4x vmcnt(8) checkpoints) but NO
// sched_barrier(0), NO asm lgkmcnt, ONE barrier per phase: the m141 lesson
// says order-pinning defeats the compiler's own fine-grained lgkmcnt
// scheduling (510 TF pathology ~ our 570-712 TF measurements). setprio pairs
// pin each MFMA cluster to its phase (side-effecting -> scheduling fence).
// (R13 == R12 resubmit: previous round hit GPUAcquisitionTimeout, no data.)

using f32x4 = __attribute__((ext_vector_type(4))) float;
using s16x8 = __attribute__((ext_vector_type(8))) short;

__device__ __forceinline__ void gload_lds16(const short* g, short* l) {
  __builtin_amdgcn_global_load_lds(
      (const __attribute__((address_space(1))) unsigned int*)g,
      (__attribute__((address_space(3))) unsigned int*)l, 16, 0, 0);
}

// -------- 256^2 8-phase GEMM (light): C[M,N] = A[M,K] * B[N,K]^T + bias, relu
// grid = (N/256, M/256), block = 512 (8 waves, 2M x 4N). K % 128 == 0.
// LDS per operand: [buf][kk][256 rows][32 k] bf16; row = 4 chunks of 16 B,
// slot = chunk ^ ((row>>1)&3) (conflict-free, measured 0 in R9/R11).
// Publish schedule (verified-in-harness, R11): checkpoints vmcnt(8) at
// P2/P4/P6/P8; steady-state publish age 4-5 phases; tail drains 8->4->0->0.
template <bool SUML>
__global__ __launch_bounds__(512, 2) void gemm256L(
    const short* __restrict__ A, const short* __restrict__ B,
    const float* __restrict__ bias, void* __restrict__ Cv, int K, int lda,
    int ldb, int ldc, int split) {
  __shared__ __align__(16) short As[2 * 2 * 8192];
  __shared__ __align__(16) short Bs[2 * 2 * 8192];

  const int t = threadIdx.x;
  const int lane = t & 63;
  const int w = t >> 6;
  const int wm = w >> 2;
  const int wn = w & 3;

  unsigned bx = blockIdx.x, by = blockIdx.y;
  {
    unsigned flat = by * gridDim.x + bx;
    unsigned total = gridDim.x * gridDim.y;
    if ((total & 7u) == 0) {
      unsigned nf = (flat & 7u) * (total >> 3) + (flat >> 3);
      bx = nf % gridDim.x;
      by = nf / gridDim.x;
    }
  }
  const int m0 = by * 256;
  const int n0 = bx * 256;

  const short* gA[2];
  const short* gB[2];
  short* lA[2];
  short* lB[2];
#pragma unroll
  for (int q = 0; q < 2; ++q) {
    const int r = (w * 2 + q) * 16 + (lane >> 2);
    const int cg = (lane & 3) ^ ((r >> 1) & 3);
    gA[q] = A + (long)(m0 + r) * lda + cg * 8;
    gB[q] = B + (long)(n0 + r) * ldb + cg * 8;
    lA[q] = As + (w * 2 + q) * 512;
    lB[q] = Bs + (w * 2 + q) * 512;
  }

  const int c4 = lane >> 4;
  const int rA0 = wm * 128 + (lane & 15);
  const int rB0 = wn * 64 + (lane & 15);
  const int aoff0 = rA0 * 32 + ((c4 ^ ((rA0 >> 1) & 3)) * 8);
  const int boff0 = rB0 * 32 + ((c4 ^ ((rB0 >> 1) & 3)) * 8);

  f32x4 acc[8][4] = {};
  s16x8 af[8], bf[2];

  const int nIter = K >> 7;

  auto stgA = [&](int koff, int roff) {
#pragma unroll
    for (int q = 0; q < 2; ++q) gload_lds16(gA[q] + koff, lA[q] + roff);
  };
  auto stgB = [&](int koff, int roff) {
#pragma unroll
    for (int q = 0; q < 2; ++q) gload_lds16(gB[q] + koff, lB[q] + roff);
  };
  auto rdA = [&](int reg) {
#pragma unroll
    for (int m = 0; m < 8; ++m)
      af[m] = *(const s16x8*)(As + reg + aoff0 + m * 512);
  };
  auto rdB = [&](int reg, int np) {
#pragma unroll
    for (int n = 0; n < 2; ++n)
      bf[n] = *(const s16x8*)(Bs + reg + boff0 + (np * 2 + n) * 512);
  };
  auto mf16 = [&](int np) {
    __builtin_amdgcn_s_setprio(1);
#pragma unroll
    for (int m = 0; m < 8; ++m)
#pragma unroll
      for (int n = 0; n < 2; ++n)
        acc[m][np * 2 + n] = __builtin_amdgcn_mfma_f32_16x16x32_bf16(
            af[m], bf[n], acc[m][np * 2 + n], 0, 0, 0);
    __builtin_amdgcn_s_setprio(0);
  };

  // prologue: stage (0).k0,(0).k1,(1).k0; publish (0).k0
  stgA(0, 0);
  stgB(0, 0);
  stgA(32, 8192);
  stgB(32, 8192);
  stgA(64, 16384);
  stgB(64, 16384);
  asm volatile("s_waitcnt vmcnt(8)" ::: "memory");
  __builtin_amdgcn_s_barrier();

  for (int i = 0; i < nIter; ++i) {
    const int kb = i * 128;
    const bool more = (i + 1 < nIter);

    // P1: stage A(2i+1).k1 -> buf1.k1; compute (buf0,kk0,nf01)
    stgA(kb + 96, 24576);
    rdA(0);
    rdB(0, 0);
    mf16(0);
    __builtin_amdgcn_s_barrier();

    // P2: stage B(2i+1).k1; compute (buf0,kk0,nf23); publish (2i).k1
    stgB(kb + 96, 24576);
    rdB(0, 1);
    mf16(1);
    asm volatile("s_waitcnt vmcnt(8)" ::: "memory");
    __builtin_amdgcn_s_barrier();

    // P3: stage A(2i+2).k0 -> buf0.k0; compute (buf0,kk1,nf01)
    if (more) stgA(kb + 128, 0);
    rdA(8192);
    rdB(8192, 0);
    mf16(0);
    __builtin_amdgcn_s_barrier();

    // P4: stage B(2i+2).k0; compute (buf0,kk1,nf23); publish (2i+1).k0
    if (more) stgB(kb + 128, 0);
    rdB(8192, 1);
    mf16(1);
    if (more) {
      asm volatile("s_waitcnt vmcnt(8)" ::: "memory");
    } else {
      asm volatile("s_waitcnt vmcnt(4)" ::: "memory");
    }
    __builtin_amdgcn_s_barrier();

    // P5: stage A(2i+2).k1 -> buf0.k1; compute (buf1,kk0,nf01)
    if (more) stgA(kb + 160, 8192);
    rdA(16384);
    rdB(16384, 0);
    mf16(0);
    __builtin_amdgcn_s_barrier();

    // P6: stage B(2i+2).k1; compute (buf1,kk0,nf23); publish (2i+1).k1
    if (more) stgB(kb + 160, 8192);
    rdB(16384, 1);
    mf16(1);
    if (more) {
      asm volatile("s_waitcnt vmcnt(8)" ::: "memory");
    } else {
      asm volatile("s_waitcnt vmcnt(0)" ::: "memory");
    }
    __builtin_amdgcn_s_barrier();

    // P7: stage A(2i+3).k0 -> buf1.k0; compute (buf1,kk1,nf01)
    if (more) stgA(kb + 192, 16384);
    rdA(24576);
    rdB(24576, 0);
    mf16(0);
    __builtin_amdgcn_s_barrier();

    // P8: stage B(2i+3).k0; compute (buf1,kk1,nf23); publish (2i+2).k0
    if (more) stgB(kb + 192, 16384);
    rdB(24576, 1);
    mf16(1);
    if (more) {
      asm volatile("s_waitcnt vmcnt(8)" ::: "memory");
    } else {
      asm volatile("s_waitcnt vmcnt(0)" ::: "memory");
    }
    __builtin_amdgcn_s_barrier();
  }

  // epilogue: C/D layout col=lane&15, row=(lane>>4)*4+reg
  const int ccol = lane & 15;
  const int crow = (lane >> 4) * 4;
  if constexpr (!SUML) {
#pragma unroll
    for (int j = 0; j < 4; ++j) {
      const int col = n0 + wn * 64 + j * 16 + ccol;
      const float bj = bias[col];
#pragma unroll
      for (int m = 0; m < 8; ++m) {
        const int row0 = m0 + wm * 128 + m * 16 + crow;
#pragma unroll
        for (int r = 0; r < 4; ++r) {
          float x = fmaxf(acc[m][j][r] + bj, 0.f);
          ((__hip_bfloat16*)Cv)[(long)(row0 + r) * ldc + col] =
              __float2bfloat16(x);
        }
      }
    }
  } else {
    __shared__ float ssum[256];
    __syncthreads();
    if (t < 256) ssum[t] = 0.f;
    __syncthreads();
#pragma unroll
    for (int j = 0; j < 4; ++j) {
      const int lcol = wn * 64 + j * 16 + ccol;
      const float bj = bias[n0 + lcol];
      float part = 0.f;
#pragma unroll
      for (int m = 0; m < 8; ++m)
#pragma unroll
        for (int r = 0; r < 4; ++r) part += fmaxf(acc[m][j][r] + bj, 0.f);
      atomicAdd(&ssum[lcol], part);
    }
    __syncthreads();
    if (t < 256) {
      int rb2 = m0 >> 8;
      const int side = rb2 >= split;
      rb2 -= side * split;
      atomicAdd((float*)Cv + (long)rb2 * ldc + side * (ldc >> 1) + n0 + t,
                ssum[t]);
    }
  }
}

// ---------------- GEMM: C[M,N] = A[M,K] * B[N,K]^T (+bias, relu) ----------------
// grid = (N/128, M/128, batch), block = 256. K % 64 == 0. Proven R8 kernel.
template <bool RELU, bool OUT_BF16, bool HAS_BIAS, bool SUML, bool CONCAT>
__global__ __launch_bounds__(256, 4) void gemm_nt(
    const short* __restrict__ A, const short* __restrict__ B,
    const float* __restrict__ bias, void* __restrict__ Cv, int K, int lda,
    int ldb, int ldc, long sA, long sB, long sC, const float* __restrict__ cs1,
    const float* __restrict__ cs2, int cBh) {
  __shared__ __align__(16) short As[128 * 64];
  __shared__ __align__(16) short Bs[128 * 64];
  const int t = threadIdx.x;
  const int lane = t & 63;
  const int wave = t >> 6;

  unsigned flat = (blockIdx.z * gridDim.y + blockIdx.y) * gridDim.x + blockIdx.x;
  const unsigned total = gridDim.x * gridDim.y * gridDim.z;
  unsigned bx = blockIdx.x, by = blockIdx.y, bz = blockIdx.z;
  if ((total & 7u) == 0) {
    unsigned nf = (flat & 7u) * (total >> 3) + (flat >> 3);
    bx = nf % gridDim.x;
    unsigned rest = nf / gridDim.x;
    by = rest % gridDim.y;
    bz = rest / gridDim.y;
  }
  const int m0 = by * 128;
  const int n0 = bx * 128;
  const long zb = bz;

  const int srow = t >> 3;
  const int schunk = ((t & 7) ^ (srow & 7)) * 8;
  const short* ag = A + zb * sA + (long)(m0 + srow) * lda + schunk;
  const short* bg = B + zb * sB + (long)(n0 + srow) * ldb + schunk;
  const long a32 = (long)32 * lda, b32 = (long)32 * ldb;
  short* AsW = As + wave * 512;
  short* BsW = Bs + wave * 512;

  const int fr = lane & 15;
  const int kq = lane >> 4;
  int aoff[4], boff[4];
#pragma unroll
  for (int i = 0; i < 4; ++i) {
    const int ra = (wave >> 1) * 64 + i * 16 + fr;
    const int rb = (wave & 1) * 64 + i * 16 + fr;
    aoff[i] = ra * 64 + ((kq ^ (ra & 7)) * 8);
    boff[i] = rb * 64 + ((kq ^ (rb & 7)) * 8);
  }

  f32x4 acc[4][4] = {};

  for (int it = K >> 6; it > 0; --it) {
    gload_lds16(ag, AsW);
    gload_lds16(ag + a32, AsW + 2048);
    gload_lds16(ag + 2 * a32, AsW + 4096);
    gload_lds16(ag + 3 * a32, AsW + 6144);
    gload_lds16(bg, BsW);
    gload_lds16(bg + b32, BsW + 2048);
    gload_lds16(bg + 2 * b32, BsW + 4096);
    gload_lds16(bg + 3 * b32, BsW + 6144);
    ag += 64;
    bg += 64;
    __syncthreads();
#pragma unroll
    for (int kk = 0; kk < 2; ++kk) {
      const int x = kk * 32;
      s16x8 af[4], bfv[4];
#pragma unroll
      for (int i = 0; i < 4; ++i) af[i] = *(const s16x8*)(As + (aoff[i] ^ x));
#pragma unroll
      for (int j = 0; j < 4; ++j) bfv[j] = *(const s16x8*)(Bs + (boff[j] ^ x));
#pragma unroll
      for (int i = 0; i < 4; ++i)
#pragma unroll
        for (int j = 0; j < 4; ++j)
          acc[i][j] = __builtin_amdgcn_mfma_f32_16x16x32_bf16(
              af[i], bfv[j], acc[i][j], 0, 0, 0);
    }
    __syncthreads();
  }

  const int ccol = lane & 15;
  const int crow = (lane >> 4) * 4;

  if constexpr (SUML) {
    __shared__ float ssum[128];
    if (t < 128) ssum[t] = 0.f;
    __syncthreads();
#pragma unroll
    for (int j = 0; j < 4; ++j) {
      const int lcol = (wave & 1) * 64 + j * 16 + ccol;
      float bj = HAS_BIAS ? bias[n0 + lcol] : 0.f;
      float part = 0.f;
#pragma unroll
      for (int i = 0; i < 4; ++i)
#pragma unroll
        for (int r = 0; r < 4; ++r) {
          float x = acc[i][j][r] + bj;
          if (RELU) x = fmaxf(x, 0.f);
          part += x;
        }
      atomicAdd(&ssum[lcol], part);
    }
    __syncthreads();
    if (t < 128) {
      const int split = (int)sC;
      int rb2 = m0 >> 8;
      const int side = rb2 >= split;
      rb2 -= side * split;
      atomicAdd((float*)Cv + (long)rb2 * ldc + side * (ldc >> 1) + n0 + t,
                ssum[t]);
    }
  } else {
#pragma unroll
    for (int j = 0; j < 4; ++j) {
      const int col = n0 + (wave & 1) * 64 + j * 16 + ccol;
      float bj = 0.f;
      if (HAS_BIAS) bj = bias[col];
#pragma unroll
      for (int i = 0; i < 4; ++i) {
        const int row0 = m0 + (wave >> 1) * 64 + i * 16 + crow;
#pragma unroll
        for (int r = 0; r < 4; ++r) {
          float x = acc[i][j][r] + bj;
          if (RELU) x = fmaxf(x, 0.f);
          const long idx = (long)(row0 + r) * ldc + col + zb * sC;
          if (OUT_BF16)
            ((__hip_bfloat16*)Cv)[idx] = __float2bfloat16(x);
          else
            ((float*)Cv)[idx] = x;
        }
      }
    }
    if constexpr (CONCAT) {
      const int side = (int)(zb >= (long)cBh);
      const int bb = (int)zb - side * cBh;
      const float* csrc = side ? cs2 : cs1;
      const long crowbase = (long)bb * 256;
      __hip_bfloat16* Cb = (__hip_bfloat16*)Cv + zb * sC + 512 + n0;
#pragma unroll
      for (int k = 0; k < 16; ++k) {
        const int idx = k * 256 + t;
        const int r = idx >> 5;
        const int q = idx & 31;
        const float4 v =
            *(const float4*)(csrc + (crowbase + m0 + r) * 512 + n0 + q * 4);
        union {
          ushort4 u;
          __hip_bfloat16 h[4];
        } pk;
        pk.h[0] = __float2bfloat16(v.x);
        pk.h[1] = __float2bfloat16(v.y);
        pk.h[2] = __float2bfloat16(v.z);
        pk.h[3] = __float2bfloat16(v.w);
        *(ushort4*)(Cb + (long)(m0 + r) * ldc + q * 4) = pk.u;
      }
    }
  }
}

// ---------------- helpers ----------------
struct CastArgs {
  const float* src[6];
  __hip_bfloat16* dst[6];
  long n[6];
};
__global__ void cast_many(CastArgs a) {
  const int w = blockIdx.y;
  long i = ((long)blockIdx.x * blockDim.x + threadIdx.x) * 4;
  if (i >= a.n[w]) return;
  float4 v = *(const float4*)(a.src[w] + i);
  __hip_bfloat16* o = a.dst[w] + i;
  o[0] = __float2bfloat16(v.x);
  o[1] = __float2bfloat16(v.y);
  o[2] = __float2bfloat16(v.z);
  o[3] = __float2bfloat16(v.w);
}

__global__ void cast_bf16(const float* __restrict__ in,
                          __hip_bfloat16* __restrict__ out, long n) {
  long i = ((long)blockIdx.x * blockDim.x + threadIdx.x) * 4;
  if (i >= n) return;
  float4 v = *(const float4*)(in + i);
  out[i + 0] = __float2bfloat16(v.x);
  out[i + 1] = __float2bfloat16(v.y);
  out[i + 2] = __float2bfloat16(v.z);
  out[i + 3] = __float2bfloat16(v.w);
}

__global__ void prep_sent(const float* __restrict__ s1,
                          const float* __restrict__ s2,
                          __hip_bfloat16* __restrict__ S12b,
                          __hip_bfloat16* __restrict__ STbase, int Bh) {
  __shared__ float tile[32][33];
  const int z = blockIdx.z;
  const int e0 = blockIdx.x * 32;
  const int l0 = blockIdx.y * 32;
  const int side = z >= Bh;
  const int b = z - side * Bh;
  const float* ib = (side ? s2 : s1) + (long)b * 131072;
  __hip_bfloat16* on = S12b + (long)z * 131072;
  __hip_bfloat16* ot = STbase + (long)(side ? b : (Bh + b)) * 131072;
  const int tx = threadIdx.x, ty = threadIdx.y;
#pragma unroll
  for (int k = 0; k < 4; ++k) {
    const int l = l0 + ty + 8 * k;
    const float v = ib[(long)l * 512 + e0 + tx];
    on[(long)l * 512 + e0 + tx] = __float2bfloat16(v);
    tile[ty + 8 * k][tx] = v;
  }
  __syncthreads();
#pragma unroll
  for (int k = 0; k < 4; ++k)
    ot[(long)(e0 + ty + 8 * k) * 256 + l0 + tx] =
        __float2bfloat16(tile[tx][ty + 8 * k]);
}

__global__ void softmax_rows(const float* __restrict__ E,
                             __hip_bfloat16* __restrict__ W) {
  const long row = blockIdx.x;
  const int t = threadIdx.x;
  const float x = E[row * 256 + t];
  float m = x;
  for (int o = 32; o > 0; o >>= 1) m = fmaxf(m, __shfl_xor(m, o));
  __shared__ float red[4];
  if ((t & 63) == 0) red[t >> 6] = m;
  __syncthreads();
  m = fmaxf(fmaxf(red[0], red[1]), fmaxf(red[2], red[3]));
  const float pr = __expf(x - m);
  float s = pr;
  for (int o = 32; o > 0; o >>= 1) s += __shfl_xor(s, o);
  __shared__ float red2[4];
  if ((t & 63) == 0) red2[t >> 6] = s;
  __syncthreads();
  s = red2[0] + red2[1] + red2[2] + red2[3];
  W[row * 256 + t] = __float2bfloat16(pr / s);
}

__global__ __launch_bounds__(256) void softmax_cols_f(
    const float* __restrict__ E, __hip_bfloat16* __restrict__ W) {
  __shared__ float tile[256][65];
  __shared__ float mred[4][64], sred[4][64];
  const int b = blockIdx.y;
  const int j0 = blockIdx.x * 64;
  const int t = threadIdx.x;
  const int jl = t & 63, s = t >> 6;
  const float* Eb = E + (long)b * 65536 + j0;
#pragma unroll
  for (int k = 0; k < 64; ++k) {
    const int i = k * 4 + s;
    tile[i][jl] = Eb[(long)i * 256 + jl];
  }
  __syncthreads();
  float m = -3.4e38f;
#pragma unroll 8
  for (int r = 0; r < 64; ++r) m = fmaxf(m, tile[s * 64 + r][jl]);
  mred[s][jl] = m;
  __syncthreads();
  m = fmaxf(fmaxf(mred[0][jl], mred[1][jl]), fmaxf(mred[2][jl], mred[3][jl]));
  float sum = 0.f;
#pragma unroll 8
  for (int r = 0; r < 64; ++r) sum += __expf(tile[s * 64 + r][jl] - m);
  sred[s][jl] = sum;
  __syncthreads();
  const int jw = t >> 2;
  const int ib = t & 3;
  const float mj = fmaxf(fmaxf(mred[0][jw], mred[1][jw]),
                         fmaxf(mred[2][jw], mred[3][jw]));
  const float isj =
      1.0f / (sred[0][jw] + sred[1][jw] + sred[2][jw] + sred[3][jw]);
  __hip_bfloat16* Wb = W + (long)b * 65536 + (long)(j0 + jw) * 256 + ib * 64;
#pragma unroll 8
  for (int r = 0; r < 64; ++r)
    Wb[r] = __float2bfloat16(__expf(tile[ib * 64 + r][jw] - mj) * isj);
}

__global__ void final_lin(const __hip_bfloat16* __restrict__ h2,
                          const float* __restrict__ w,
                          const float* __restrict__ bs,
                          float* __restrict__ out) {
  const int b = blockIdx.x;
  const int t = threadIdx.x;
  float p0 = 0.f, p1 = 0.f, p2 = 0.f;
  for (int k = t; k < 1024; k += 256) {
    const float x = __bfloat162float(h2[(long)b * 1024 + k]);
    p0 += x * w[k];
    p1 += x * w[1024 + k];
    p2 += x * w[2048 + k];
  }
  for (int o = 32; o > 0; o >>= 1) {
    p0 += __shfl_xor(p0, o);
    p1 += __shfl_xor(p1, o);
    p2 += __shfl_xor(p2, o);
  }
  __shared__ float r[4][3];
  if ((t & 63) == 0) {
    r[t >> 6][0] = p0;
    r[t >> 6][1] = p1;
    r[t >> 6][2] = p2;
  }
  __syncthreads();
  if (t < 3)
    out[b * 3 + t] = r[0][t] + r[1][t] + r[2][t] + r[3][t] + bs[t];
}

extern "C" void kernel_launch(void* const* d_in, const int* in_sizes, int n_in,
                              void* d_out, int out_size, void* d_ws,
                              size_t ws_size, hipStream_t stream) {
  const float* sent1 = (const float*)d_in[0];
  const float* sent2 = (const float*)d_in[1];
  const float* f_w1 = (const float*)d_in[2];
  const float* f_b1 = (const float*)d_in[3];
  const float* f_w2 = (const float*)d_in[4];
  const float* f_b2 = (const float*)d_in[5];
  const float* g_w1 = (const float*)d_in[6];
  const float* g_b1 = (const float*)d_in[7];
  const float* g_w2 = (const float*)d_in[8];
  const float* g_b2 = (const float*)d_in[9];
  const float* h_w1 = (const float*)d_in[10];
  const float* h_b1 = (const float*)d_in[11];
  const float* h_w2 = (const float*)d_in[12];
  const float* h_b2 = (const float*)d_in[13];
  const float* fin_w = (const float*)d_in[14];
  const float* fin_b = (const float*)d_in[15];

  char* p = (char*)d_ws;
  auto take = [&](size_t n) {
    char* r = p;
    p += (n + 255) & ~(size_t)255;
    return r;
  };
  const int Bh = (ws_size >= (size_t)220 * 1024 * 1024) ? 64 : 32;
  const int chunks = 128 / Bh;
  const long R = (long)Bh * 256;

  short* Wf1 = (short*)take(1024L * 512 * 2);
  short* Wf2 = (short*)take(1024L * 1024 * 2);
  short* Wg1 = (short*)take(1024L * 1024 * 2);
  short* Wg2 = (short*)take(1024L * 1024 * 2);
  short* Wh1 = (short*)take(1024L * 2048 * 2);
  short* Wh2 = (short*)take(1024L * 1024 * 2);
  float* SUMF = (float*)take(128L * 2048 * 4);
  short* scat = (short*)take(128L * 2048 * 2);
  short* hh = (short*)take(128L * 1024 * 2);
  short* hf = (short*)take(128L * 1024 * 2);
  char* Areg = take(2 * R * 1024 * 2);  // FHID -> GHID
  char* Breg = take(2 * R * 1024 * 2);  // F12 -> CC12
  char* Creg = take(2 * R * 512 * 2);   // S12b -> E1|W1A|W2A
  char* Dreg = take(2 * R * 512 * 2);   // [S2T | S1T]
  (void)in_sizes; (void)n_in; (void)out_size;

  short* FHID = (short*)Areg;
  short* GHID = (short*)Areg;
  short* F12 = (short*)Breg;
  short* CC12 = (short*)Breg;
  short* S12b = (short*)Creg;
  float* E1 = (float*)Creg;
  short* W1A = (short*)(Creg + (long)Bh * 262144);
  short* W2A = W1A + (long)Bh * 65536;
  short* ST = (short*)Dreg;

  hipMemsetAsync(SUMF, 0, 128L * 2048 * 4, stream);

  CastArgs ca;
  ca.src[0] = f_w1; ca.dst[0] = (__hip_bfloat16*)Wf1; ca.n[0] = 524288;
  ca.src[1] = f_w2; ca.dst[1] = (__hip_bfloat16*)Wf2; ca.n[1] = 1048576;
  ca.src[2] = g_w1; ca.dst[2] = (__hip_bfloat16*)Wg1; ca.n[2] = 1048576;
  ca.src[3] = g_w2; ca.dst[3] = (__hip_bfloat16*)Wg2; ca.n[3] = 1048576;
  ca.src[4] = h_w1; ca.dst[4] = (__hip_bfloat16*)Wh1; ca.n[4] = 2097152;
  ca.src[5] = h_w2; ca.dst[5] = (__hip_bfloat16*)Wh2; ca.n[5] = 1048576;
  cast_many<<<dim3(2048, 6), 256, 0, stream>>>(ca);

  for (int c = 0; c < chunks; ++c) {
    const float* s1 = sent1 + (long)c * R * 512;
    const float* s2 = sent2 + (long)c * R * 512;
    float* SUMF_c = SUMF + (long)c * Bh * 2048;
    const int MT = (int)(2 * R / 128);

    prep_sent<<<dim3(16, 8, 2 * Bh), dim3(32, 8), 0, stream>>>(
        s1, s2, (__hip_bfloat16*)S12b, (__hip_bfloat16*)ST, Bh);

    // ---- attend MLP f (merged sides, M = 2R), proven 128^2 kernel ----
    gemm_nt<true, true, true, false, false><<<dim3(8, MT, 1), 256, 0, stream>>>(
        S12b, Wf1, f_b1, FHID, 512, 512, 512, 1024, 0, 0, 0, nullptr, nullptr, 0);
    gemm_nt<true, true, true, false, false><<<dim3(8, MT, 1), 256, 0, stream>>>(
        FHID, Wf2, f_b2, F12, 1024, 1024, 1024, 1024, 0, 0, 0, nullptr, nullptr, 0);

    // ---- e1 = F1 F2^T (batched fp32; overwrites S12b region) ----
    gemm_nt<false, false, false, false, false><<<dim3(2, 2, Bh), 256, 0, stream>>>(
        F12, F12 + R * 1024, nullptr, E1, 1024, 1024, 1024, 256, 256L * 1024,
        256L * 1024, 65536, nullptr, nullptr, 0);

    // ---- softmaxes ----
    softmax_rows<<<Bh * 256, 256, 0, stream>>>(E1, (__hip_bfloat16*)W1A);
    softmax_cols_f<<<dim3(4, Bh), 256, 0, stream>>>(E1, (__hip_bfloat16*)W2A);

    // ---- att (merged) + fused coalesced concat right-half fill ----
    gemm_nt<false, true, false, false, true><<<dim3(4, 2, 2 * Bh), 256, 0, stream>>>(
        W1A, ST, nullptr, CC12, 256, 256, 256, 1024, 65536, 131072, 262144,
        s1, s2, Bh);

    // ---- compare MLP g: g1 = PROBE (light 8-phase 256^2), g2 = proven ----
    gemm256L<false><<<dim3(4, (int)(2 * R / 256)), 512, 0, stream>>>(
        CC12, Wg1, g_b1, GHID, 1024, 1024, 1024, 1024, 0);
    gemm_nt<true, false, true, true, false><<<dim3(8, MT, 1), 256, 0, stream>>>(
        GHID, Wg2, g_b2, SUMF_c, 1024, 1024, 1024, 2048, 0, 0, Bh, nullptr, nullptr, 0);
  }

  // ---- aggregate MLP h + final linear ----
  cast_bf16<<<256, 256, 0, stream>>>(SUMF, (__hip_bfloat16*)scat, 262144);
  gemm_nt<true, true, true, false, false><<<dim3(8, 1, 1), 256, 0, stream>>>(
      scat, Wh1, h_b1, hh, 2048, 2048, 2048, 1024, 0, 0, 0, nullptr, nullptr, 0);
  gemm_nt<true, true, true, false, false><<<dim3(8, 1, 1), 256, 0, stream>>>(
      hh, Wh2, h_b2, hf, 1024, 1024, 1024, 1024, 0, 0, 0, nullptr, nullptr, 0);
  final_lin<<<128, 256, 0, stream>>>((__hip_bfloat16*)hf, fin_w, fin_b,
                                     (float*)d_out);
}

// Round 6
// 936.513 us; speedup vs baseline: 1.3586x; 1.0888x over previous
//
#include <hip/hip_runtime.h>
#include <hip/hip_bf16.h>

// Decomposable attention, bf16-MFMA pipeline, chunked (Bh per side per chunk).
// R14: full revert to R8's proven 128^2 gemm_nt for all big GEMMs (932 TF;
// three 256^2 8-phase schedule variants all measured WORSE: 97/120/112 us vs
// 74 us -> arc abandoned per pre-commitment). New: e1_rowsm fuses the row
// softmax into e1's epilogue (tile 64x256: each wave owns 16 full rows; row
// reduce = shfl_xor 1/2/4/8 within the 16-lane col group), writing W1A bf16
// directly + E1 fp32 for the col pass. Deletes softmax_rows (64MB read +
// 32MB write + launch per chunk).

using f32x4 = __attribute__((ext_vector_type(4))) float;
using s16x8 = __attribute__((ext_vector_type(8))) short;

__device__ __forceinline__ void gload_lds16(const short* g, short* l) {
  __builtin_amdgcn_global_load_lds(
      (const __attribute__((address_space(1))) unsigned int*)g,
      (__attribute__((address_space(3))) unsigned int*)l, 16, 0, 0);
}

// ---------------- GEMM: C[M,N] = A[M,K] * B[N,K]^T (+bias, relu) ----------------
// grid = (N/128, M/128, batch), block = 256. K % 64 == 0. Proven R8 kernel.
template <bool RELU, bool OUT_BF16, bool HAS_BIAS, bool SUML, bool CONCAT>
__global__ __launch_bounds__(256, 4) void gemm_nt(
    const short* __restrict__ A, const short* __restrict__ B,
    const float* __restrict__ bias, void* __restrict__ Cv, int K, int lda,
    int ldb, int ldc, long sA, long sB, long sC, const float* __restrict__ cs1,
    const float* __restrict__ cs2, int cBh) {
  __shared__ __align__(16) short As[128 * 64];
  __shared__ __align__(16) short Bs[128 * 64];
  const int t = threadIdx.x;
  const int lane = t & 63;
  const int wave = t >> 6;

  unsigned flat = (blockIdx.z * gridDim.y + blockIdx.y) * gridDim.x + blockIdx.x;
  const unsigned total = gridDim.x * gridDim.y * gridDim.z;
  unsigned bx = blockIdx.x, by = blockIdx.y, bz = blockIdx.z;
  if ((total & 7u) == 0) {
    unsigned nf = (flat & 7u) * (total >> 3) + (flat >> 3);
    bx = nf % gridDim.x;
    unsigned rest = nf / gridDim.x;
    by = rest % gridDim.y;
    bz = rest / gridDim.y;
  }
  const int m0 = by * 128;
  const int n0 = bx * 128;
  const long zb = bz;

  const int srow = t >> 3;
  const int schunk = ((t & 7) ^ (srow & 7)) * 8;
  const short* ag = A + zb * sA + (long)(m0 + srow) * lda + schunk;
  const short* bg = B + zb * sB + (long)(n0 + srow) * ldb + schunk;
  const long a32 = (long)32 * lda, b32 = (long)32 * ldb;
  short* AsW = As + wave * 512;
  short* BsW = Bs + wave * 512;

  const int fr = lane & 15;
  const int kq = lane >> 4;
  int aoff[4], boff[4];
#pragma unroll
  for (int i = 0; i < 4; ++i) {
    const int ra = (wave >> 1) * 64 + i * 16 + fr;
    const int rb = (wave & 1) * 64 + i * 16 + fr;
    aoff[i] = ra * 64 + ((kq ^ (ra & 7)) * 8);
    boff[i] = rb * 64 + ((kq ^ (rb & 7)) * 8);
  }

  f32x4 acc[4][4] = {};

  for (int it = K >> 6; it > 0; --it) {
    gload_lds16(ag, AsW);
    gload_lds16(ag + a32, AsW + 2048);
    gload_lds16(ag + 2 * a32, AsW + 4096);
    gload_lds16(ag + 3 * a32, AsW + 6144);
    gload_lds16(bg, BsW);
    gload_lds16(bg + b32, BsW + 2048);
    gload_lds16(bg + 2 * b32, BsW + 4096);
    gload_lds16(bg + 3 * b32, BsW + 6144);
    ag += 64;
    bg += 64;
    __syncthreads();
#pragma unroll
    for (int kk = 0; kk < 2; ++kk) {
      const int x = kk * 32;
      s16x8 af[4], bfv[4];
#pragma unroll
      for (int i = 0; i < 4; ++i) af[i] = *(const s16x8*)(As + (aoff[i] ^ x));
#pragma unroll
      for (int j = 0; j < 4; ++j) bfv[j] = *(const s16x8*)(Bs + (boff[j] ^ x));
#pragma unroll
      for (int i = 0; i < 4; ++i)
#pragma unroll
        for (int j = 0; j < 4; ++j)
          acc[i][j] = __builtin_amdgcn_mfma_f32_16x16x32_bf16(
              af[i], bfv[j], acc[i][j], 0, 0, 0);
    }
    __syncthreads();
  }

  const int ccol = lane & 15;
  const int crow = (lane >> 4) * 4;

  if constexpr (SUML) {
    __shared__ float ssum[128];
    if (t < 128) ssum[t] = 0.f;
    __syncthreads();
#pragma unroll
    for (int j = 0; j < 4; ++j) {
      const int lcol = (wave & 1) * 64 + j * 16 + ccol;
      float bj = HAS_BIAS ? bias[n0 + lcol] : 0.f;
      float part = 0.f;
#pragma unroll
      for (int i = 0; i < 4; ++i)
#pragma unroll
        for (int r = 0; r < 4; ++r) {
          float x = acc[i][j][r] + bj;
          if (RELU) x = fmaxf(x, 0.f);
          part += x;
        }
      atomicAdd(&ssum[lcol], part);
    }
    __syncthreads();
    if (t < 128) {
      const int split = (int)sC;
      int rb2 = m0 >> 8;
      const int side = rb2 >= split;
      rb2 -= side * split;
      atomicAdd((float*)Cv + (long)rb2 * ldc + side * (ldc >> 1) + n0 + t,
                ssum[t]);
    }
  } else {
#pragma unroll
    for (int j = 0; j < 4; ++j) {
      const int col = n0 + (wave & 1) * 64 + j * 16 + ccol;
      float bj = 0.f;
      if (HAS_BIAS) bj = bias[col];
#pragma unroll
      for (int i = 0; i < 4; ++i) {
        const int row0 = m0 + (wave >> 1) * 64 + i * 16 + crow;
#pragma unroll
        for (int r = 0; r < 4; ++r) {
          float x = acc[i][j][r] + bj;
          if (RELU) x = fmaxf(x, 0.f);
          const long idx = (long)(row0 + r) * ldc + col + zb * sC;
          if (OUT_BF16)
            ((__hip_bfloat16*)Cv)[idx] = __float2bfloat16(x);
          else
            ((float*)Cv)[idx] = x;
        }
      }
    }
    if constexpr (CONCAT) {
      const int side = (int)(zb >= (long)cBh);
      const int bb = (int)zb - side * cBh;
      const float* csrc = side ? cs2 : cs1;
      const long crowbase = (long)bb * 256;
      __hip_bfloat16* Cb = (__hip_bfloat16*)Cv + zb * sC + 512 + n0;
#pragma unroll
      for (int k = 0; k < 16; ++k) {
        const int idx = k * 256 + t;
        const int r = idx >> 5;
        const int q = idx & 31;
        const float4 v =
            *(const float4*)(csrc + (crowbase + m0 + r) * 512 + n0 + q * 4);
        union {
          ushort4 u;
          __hip_bfloat16 h[4];
        } pk;
        pk.h[0] = __float2bfloat16(v.x);
        pk.h[1] = __float2bfloat16(v.y);
        pk.h[2] = __float2bfloat16(v.z);
        pk.h[3] = __float2bfloat16(v.w);
        *(ushort4*)(Cb + (long)(m0 + r) * ldc + q * 4) = pk.u;
      }
    }
  }
}

// -------- e1 + fused row softmax: E[i,j] = F1[i,:]*F2[j,:]; W = softmax_j(E)
// grid = (4, Bh) : bx = 64-row M-tile, by = batch. block = 256 (4 waves).
// Wave w computes rows w*16..w*16+15 x all 256 cols (16 n-frags, K=1024).
// Row r lives in one 16-lane group (col = lane&15) -> row reduce is
// shfl_xor(1,2,4,8). Writes E fp32 (for col-softmax pass) + W bf16.
__global__ __launch_bounds__(256, 4) void e1_rowsm(
    const short* __restrict__ A, const short* __restrict__ B,
    float* __restrict__ E, __hip_bfloat16* __restrict__ W) {
  __shared__ __align__(16) short As[64 * 64];
  __shared__ __align__(16) short Bs[256 * 64];
  const int t = threadIdx.x;
  const int lane = t & 63;
  const int w = t >> 6;
  const int m0 = blockIdx.x * 64;
  const long z = blockIdx.y;

  // staging geometry (identical pattern to gemm_nt): issue covers 32 rows;
  // thread t -> row t>>3, LDS slot t&7, global chunk (t&7)^(row&7).
  const int srow = t >> 3;
  const int schunk = ((t & 7) ^ (srow & 7)) * 8;
  const short* ag = A + z * 262144 + (long)(m0 + srow) * 1024 + schunk;
  const short* bg = B + z * 262144 + (long)srow * 1024 + schunk;
  short* AsW = As + w * 512;
  short* BsW = Bs + w * 512;

  const int fr = lane & 15;
  const int kq = lane >> 4;
  const int ra = w * 16 + fr;
  const int aoff = ra * 64 + ((kq ^ (ra & 7)) * 8);
  int boff[16];
#pragma unroll
  for (int j = 0; j < 16; ++j) {
    const int rb = j * 16 + fr;
    boff[j] = rb * 64 + ((kq ^ (rb & 7)) * 8);
  }

  f32x4 acc[16] = {};

  for (int it = 0; it < 16; ++it) {
    gload_lds16(ag, AsW);              // A rows 0..31
    gload_lds16(ag + 32768, AsW + 2048);  // A rows 32..63
#pragma unroll
    for (int q = 0; q < 8; ++q)        // B rows q*32..q*32+31
      gload_lds16(bg + (long)q * 32768, BsW + q * 2048);
    ag += 64;
    bg += 64;
    __syncthreads();
#pragma unroll
    for (int kk = 0; kk < 2; ++kk) {
      const int x = kk * 32;
      const s16x8 af = *(const s16x8*)(As + (aoff ^ x));
#pragma unroll
      for (int j = 0; j < 16; ++j) {
        const s16x8 bf = *(const s16x8*)(Bs + (boff[j] ^ x));
        acc[j] = __builtin_amdgcn_mfma_f32_16x16x32_bf16(af, bf, acc[j], 0, 0, 0);
      }
    }
    __syncthreads();
  }

  // epilogue: C/D layout col=lane&15, row=(lane>>4)*4+r (within 16x16 frag)
  const int crow = kq * 4;
  float mx[4] = {-3.4e38f, -3.4e38f, -3.4e38f, -3.4e38f};
#pragma unroll
  for (int j = 0; j < 16; ++j)
#pragma unroll
    for (int r = 0; r < 4; ++r) mx[r] = fmaxf(mx[r], acc[j][r]);
#pragma unroll
  for (int o = 1; o < 16; o <<= 1)
#pragma unroll
    for (int r = 0; r < 4; ++r) mx[r] = fmaxf(mx[r], __shfl_xor(mx[r], o));
  float sm[4] = {0.f, 0.f, 0.f, 0.f};
#pragma unroll
  for (int j = 0; j < 16; ++j)
#pragma unroll
    for (int r = 0; r < 4; ++r) sm[r] += __expf(acc[j][r] - mx[r]);
#pragma unroll
  for (int o = 1; o < 16; o <<= 1)
#pragma unroll
    for (int r = 0; r < 4; ++r) sm[r] += __shfl_xor(sm[r], o);
  float is[4];
#pragma unroll
  for (int r = 0; r < 4; ++r) is[r] = 1.0f / sm[r];

  float* Eb = E + z * 65536;
  __hip_bfloat16* Wb = W + z * 65536;
#pragma unroll
  for (int j = 0; j < 16; ++j) {
    const int col = j * 16 + fr;
#pragma unroll
    for (int r = 0; r < 4; ++r) {
      const long idx = (long)(m0 + w * 16 + crow + r) * 256 + col;
      Eb[idx] = acc[j][r];
      Wb[idx] = __float2bfloat16(__expf(acc[j][r] - mx[r]) * is[r]);
    }
  }
}

// ---------------- helpers ----------------
struct CastArgs {
  const float* src[6];
  __hip_bfloat16* dst[6];
  long n[6];
};
__global__ void cast_many(CastArgs a) {
  const int w = blockIdx.y;
  long i = ((long)blockIdx.x * blockDim.x + threadIdx.x) * 4;
  if (i >= a.n[w]) return;
  float4 v = *(const float4*)(a.src[w] + i);
  __hip_bfloat16* o = a.dst[w] + i;
  o[0] = __float2bfloat16(v.x);
  o[1] = __float2bfloat16(v.y);
  o[2] = __float2bfloat16(v.z);
  o[3] = __float2bfloat16(v.w);
}

__global__ void cast_bf16(const float* __restrict__ in,
                          __hip_bfloat16* __restrict__ out, long n) {
  long i = ((long)blockIdx.x * blockDim.x + threadIdx.x) * 4;
  if (i >= n) return;
  float4 v = *(const float4*)(in + i);
  out[i + 0] = __float2bfloat16(v.x);
  out[i + 1] = __float2bfloat16(v.y);
  out[i + 2] = __float2bfloat16(v.z);
  out[i + 3] = __float2bfloat16(v.w);
}

__global__ void prep_sent(const float* __restrict__ s1,
                          const float* __restrict__ s2,
                          __hip_bfloat16* __restrict__ S12b,
                          __hip_bfloat16* __restrict__ STbase, int Bh) {
  __shared__ float tile[32][33];
  const int z = blockIdx.z;
  const int e0 = blockIdx.x * 32;
  const int l0 = blockIdx.y * 32;
  const int side = z >= Bh;
  const int b = z - side * Bh;
  const float* ib = (side ? s2 : s1) + (long)b * 131072;
  __hip_bfloat16* on = S12b + (long)z * 131072;
  __hip_bfloat16* ot = STbase + (long)(side ? b : (Bh + b)) * 131072;
  const int tx = threadIdx.x, ty = threadIdx.y;
#pragma unroll
  for (int k = 0; k < 4; ++k) {
    const int l = l0 + ty + 8 * k;
    const float v = ib[(long)l * 512 + e0 + tx];
    on[(long)l * 512 + e0 + tx] = __float2bfloat16(v);
    tile[ty + 8 * k][tx] = v;
  }
  __syncthreads();
#pragma unroll
  for (int k = 0; k < 4; ++k)
    ot[(long)(e0 + ty + 8 * k) * 256 + l0 + tx] =
        __float2bfloat16(tile[tx][ty + 8 * k]);
}

__global__ __launch_bounds__(256) void softmax_cols_f(
    const float* __restrict__ E, __hip_bfloat16* __restrict__ W) {
  __shared__ float tile[256][65];
  __shared__ float mred[4][64], sred[4][64];
  const int b = blockIdx.y;
  const int j0 = blockIdx.x * 64;
  const int t = threadIdx.x;
  const int jl = t & 63, s = t >> 6;
  const float* Eb = E + (long)b * 65536 + j0;
#pragma unroll
  for (int k = 0; k < 64; ++k) {
    const int i = k * 4 + s;
    tile[i][jl] = Eb[(long)i * 256 + jl];
  }
  __syncthreads();
  float m = -3.4e38f;
#pragma unroll 8
  for (int r = 0; r < 64; ++r) m = fmaxf(m, tile[s * 64 + r][jl]);
  mred[s][jl] = m;
  __syncthreads();
  m = fmaxf(fmaxf(mred[0][jl], mred[1][jl]), fmaxf(mred[2][jl], mred[3][jl]));
  float sum = 0.f;
#pragma unroll 8
  for (int r = 0; r < 64; ++r) sum += __expf(tile[s * 64 + r][jl] - m);
  sred[s][jl] = sum;
  __syncthreads();
  const int jw = t >> 2;
  const int ib = t & 3;
  const float mj = fmaxf(fmaxf(mred[0][jw], mred[1][jw]),
                         fmaxf(mred[2][jw], mred[3][jw]));
  const float isj =
      1.0f / (sred[0][jw] + sred[1][jw] + sred[2][jw] + sred[3][jw]);
  __hip_bfloat16* Wb = W + (long)b * 65536 + (long)(j0 + jw) * 256 + ib * 64;
#pragma unroll 8
  for (int r = 0; r < 64; ++r)
    Wb[r] = __float2bfloat16(__expf(tile[ib * 64 + r][jw] - mj) * isj);
}

__global__ void final_lin(const __hip_bfloat16* __restrict__ h2,
                          const float* __restrict__ w,
                          const float* __restrict__ bs,
                          float* __restrict__ out) {
  const int b = blockIdx.x;
  const int t = threadIdx.x;
  float p0 = 0.f, p1 = 0.f, p2 = 0.f;
  for (int k = t; k < 1024; k += 256) {
    const float x = __bfloat162float(h2[(long)b * 1024 + k]);
    p0 += x * w[k];
    p1 += x * w[1024 + k];
    p2 += x * w[2048 + k];
  }
  for (int o = 32; o > 0; o >>= 1) {
    p0 += __shfl_xor(p0, o);
    p1 += __shfl_xor(p1, o);
    p2 += __shfl_xor(p2, o);
  }
  __shared__ float r[4][3];
  if ((t & 63) == 0) {
    r[t >> 6][0] = p0;
    r[t >> 6][1] = p1;
    r[t >> 6][2] = p2;
  }
  __syncthreads();
  if (t < 3)
    out[b * 3 + t] = r[0][t] + r[1][t] + r[2][t] + r[3][t] + bs[t];
}

extern "C" void kernel_launch(void* const* d_in, const int* in_sizes, int n_in,
                              void* d_out, int out_size, void* d_ws,
                              size_t ws_size, hipStream_t stream) {
  const float* sent1 = (const float*)d_in[0];
  const float* sent2 = (const float*)d_in[1];
  const float* f_w1 = (const float*)d_in[2];
  const float* f_b1 = (const float*)d_in[3];
  const float* f_w2 = (const float*)d_in[4];
  const float* f_b2 = (const float*)d_in[5];
  const float* g_w1 = (const float*)d_in[6];
  const float* g_b1 = (const float*)d_in[7];
  const float* g_w2 = (const float*)d_in[8];
  const float* g_b2 = (const float*)d_in[9];
  const float* h_w1 = (const float*)d_in[10];
  const float* h_b1 = (const float*)d_in[11];
  const float* h_w2 = (const float*)d_in[12];
  const float* h_b2 = (const float*)d_in[13];
  const float* fin_w = (const float*)d_in[14];
  const float* fin_b = (const float*)d_in[15];

  char* p = (char*)d_ws;
  auto take = [&](size_t n) {
    char* r = p;
    p += (n + 255) & ~(size_t)255;
    return r;
  };
  const int Bh = (ws_size >= (size_t)220 * 1024 * 1024) ? 64 : 32;
  const int chunks = 128 / Bh;
  const long R = (long)Bh * 256;

  short* Wf1 = (short*)take(1024L * 512 * 2);
  short* Wf2 = (short*)take(1024L * 1024 * 2);
  short* Wg1 = (short*)take(1024L * 1024 * 2);
  short* Wg2 = (short*)take(1024L * 1024 * 2);
  short* Wh1 = (short*)take(1024L * 2048 * 2);
  short* Wh2 = (short*)take(1024L * 1024 * 2);
  float* SUMF = (float*)take(128L * 2048 * 4);
  short* scat = (short*)take(128L * 2048 * 2);
  short* hh = (short*)take(128L * 1024 * 2);
  short* hf = (short*)take(128L * 1024 * 2);
  char* Areg = take(2 * R * 1024 * 2);  // FHID -> GHID
  char* Breg = take(2 * R * 1024 * 2);  // F12 -> CC12
  char* Creg = take(2 * R * 512 * 2);   // S12b -> E1|W1A|W2A
  char* Dreg = take(2 * R * 512 * 2);   // [S2T | S1T]
  (void)in_sizes; (void)n_in; (void)out_size;

  short* FHID = (short*)Areg;
  short* GHID = (short*)Areg;
  short* F12 = (short*)Breg;
  short* CC12 = (short*)Breg;
  short* S12b = (short*)Creg;
  float* E1 = (float*)Creg;
  short* W1A = (short*)(Creg + (long)Bh * 262144);
  short* W2A = W1A + (long)Bh * 65536;
  short* ST = (short*)Dreg;

  hipMemsetAsync(SUMF, 0, 128L * 2048 * 4, stream);

  CastArgs ca;
  ca.src[0] = f_w1; ca.dst[0] = (__hip_bfloat16*)Wf1; ca.n[0] = 524288;
  ca.src[1] = f_w2; ca.dst[1] = (__hip_bfloat16*)Wf2; ca.n[1] = 1048576;
  ca.src[2] = g_w1; ca.dst[2] = (__hip_bfloat16*)Wg1; ca.n[2] = 1048576;
  ca.src[3] = g_w2; ca.dst[3] = (__hip_bfloat16*)Wg2; ca.n[3] = 1048576;
  ca.src[4] = h_w1; ca.dst[4] = (__hip_bfloat16*)Wh1; ca.n[4] = 2097152;
  ca.src[5] = h_w2; ca.dst[5] = (__hip_bfloat16*)Wh2; ca.n[5] = 1048576;
  cast_many<<<dim3(2048, 6), 256, 0, stream>>>(ca);

  for (int c = 0; c < chunks; ++c) {
    const float* s1 = sent1 + (long)c * R * 512;
    const float* s2 = sent2 + (long)c * R * 512;
    float* SUMF_c = SUMF + (long)c * Bh * 2048;
    const int MT = (int)(2 * R / 128);

    prep_sent<<<dim3(16, 8, 2 * Bh), dim3(32, 8), 0, stream>>>(
        s1, s2, (__hip_bfloat16*)S12b, (__hip_bfloat16*)ST, Bh);

    // ---- attend MLP f (merged sides, M = 2R) ----
    gemm_nt<true, true, true, false, false><<<dim3(8, MT, 1), 256, 0, stream>>>(
        S12b, Wf1, f_b1, FHID, 512, 512, 512, 1024, 0, 0, 0, nullptr, nullptr, 0);
    gemm_nt<true, true, true, false, false><<<dim3(8, MT, 1), 256, 0, stream>>>(
        FHID, Wf2, f_b2, F12, 1024, 1024, 1024, 1024, 0, 0, 0, nullptr, nullptr, 0);

    // ---- e1 = F1 F2^T fused with row softmax (writes E1 fp32 + W1A bf16) ----
    e1_rowsm<<<dim3(4, Bh), 256, 0, stream>>>(
        F12, F12 + R * 1024, E1, (__hip_bfloat16*)W1A);

    // ---- column softmax (reads E1) ----
    softmax_cols_f<<<dim3(4, Bh), 256, 0, stream>>>(E1, (__hip_bfloat16*)W2A);

    // ---- att (merged) + fused coalesced concat right-half fill ----
    gemm_nt<false, true, false, false, true><<<dim3(4, 2, 2 * Bh), 256, 0, stream>>>(
        W1A, ST, nullptr, CC12, 256, 256, 256, 1024, 65536, 131072, 262144,
        s1, s2, Bh);

    // ---- compare MLP g (merged); layer2 accumulates sum-over-L ----
    gemm_nt<true, true, true, false, false><<<dim3(8, MT, 1), 256, 0, stream>>>(
        CC12, Wg1, g_b1, GHID, 1024, 1024, 1024, 1024, 0, 0, 0, nullptr, nullptr, 0);
    gemm_nt<true, false, true, true, false><<<dim3(8, MT, 1), 256, 0, stream>>>(
        GHID, Wg2, g_b2, SUMF_c, 1024, 1024, 1024, 2048, 0, 0, Bh, nullptr, nullptr, 0);
  }

  // ---- aggregate MLP h + final linear ----
  cast_bf16<<<256, 256, 0, stream>>>(SUMF, (__hip_bfloat16*)scat, 262144);
  gemm_nt<true, true, true, false, false><<<dim3(8, 1, 1), 256, 0, stream>>>(
      scat, Wh1, h_b1, hh, 2048, 2048, 2048, 1024, 0, 0, 0, nullptr, nullptr, 0);
  gemm_nt<true, true, true, false, false><<<dim3(8, 1, 1), 256, 0, stream>>>(
      hh, Wh2, h_b2, hf, 1024, 1024, 1024, 1024, 0, 0, 0, nullptr, nullptr, 0);
  final_lin<<<128, 256, 0, stream>>>((__hip_bfloat16*)hf, fin_w, fin_b,
                                     (float*)d_out);
}